// Round 10
// baseline (188.362 us; speedup 1.0000x reference)
//
#include <hip/hip_runtime.h>
#include <hip/hip_bf16.h>

typedef __bf16 bf16;
typedef __bf16 bf16x4 __attribute__((ext_vector_type(4)));
typedef __bf16 bf16x8 __attribute__((ext_vector_type(8)));
typedef float f32x4 __attribute__((ext_vector_type(4)));

#define AS1 __attribute__((address_space(1)))
#define AS3 __attribute__((address_space(3)))

__device__ __forceinline__ void gload_lds16(const void* g, void* l) {
  __builtin_amdgcn_global_load_lds((const AS1 void*)g, (AS3 void*)l, 16, 0, 0);
}

__device__ __forceinline__ float fexp2(float x) {
#if __has_builtin(__builtin_amdgcn_exp2f)
  return __builtin_amdgcn_exp2f(x);
#else
  return exp2f(x);
#endif
}

// ---------------- problem constants ----------------
#define BB 4
#define SS 2048
#define DD 1024
#define HH 16
#define MM (BB*SS)          // 8192 rows
#define LDQ 3072            // QKV fused row stride
#define NT (SS/64)          // K/V tiles per attention pass
// log2(e) / sqrt(64)  -- folded into Wq,bq so softmax runs in exp2 domain
#define QSCALE 0.18033688011112042f

// ---------------- fused prep kernel ----------------
__global__ __launch_bounds__(256) void prep(
    const float* __restrict__ x, bf16* __restrict__ xb,
    const float* __restrict__ Wq, const float* __restrict__ Wk,
    const float* __restrict__ Wv, const float* __restrict__ Wo,
    bf16* __restrict__ WtQKV, bf16* __restrict__ Wto,
    const float* __restrict__ bq, const float* __restrict__ bk,
    const float* __restrict__ bv, float* __restrict__ ball,
    int* __restrict__ flag) {
  __shared__ float t[64][65];
  const int bid = blockIdx.x;
  if (bid < 4096) {            // ---- cvt_x ----
    int i = (bid * 256 + threadIdx.x) * 8;
    float4 a = *(const float4*)&x[i];
    float4 b = *(const float4*)&x[i + 4];
    bf16x8 o;
    o[0] = (bf16)a.x; o[1] = (bf16)a.y; o[2] = (bf16)a.z; o[3] = (bf16)a.w;
    o[4] = (bf16)b.x; o[5] = (bf16)b.y; o[6] = (bf16)b.z; o[7] = (bf16)b.w;
    *(bf16x8*)&xb[i] = o;
  } else if (bid < 5120) {     // ---- wtrans ----
    int id = bid - 4096;
    int which = id >> 8;
    int bi = (id >> 4) & 15, bj = id & 15;   // bi: k-tile, bj: n-tile
    const float* W = which == 0 ? Wq : which == 1 ? Wk : which == 2 ? Wv : Wo;
    bf16* Wt = which < 3 ? WtQKV + (size_t)which * 1024 * DD : Wto;
    const float scale = (which == 0) ? QSCALE : 1.0f;
    for (int c = 0; c < 16; c++) {
      int idx = threadIdx.x + c * 256;
      int r = idx >> 6, col = idx & 63;
      t[r][col] = W[(size_t)(bi * 64 + r) * DD + bj * 64 + col];
    }
    __syncthreads();
    for (int c = 0; c < 16; c++) {
      int idx = threadIdx.x + c * 256;
      int rn = idx >> 6, ck = idx & 63;
      Wt[(size_t)(bj * 64 + rn) * DD + bi * 64 + ck] = (bf16)(t[ck][rn] * scale);
    }
  } else {                     // ---- bias concat + flag init ----
    int i = (bid - 5120) * 256 + threadIdx.x;
    if (i == 0) *flag = 1;
    float v = (i < 1024) ? bq[i] * QSCALE
                         : ((i < 2048) ? bk[i - 1024] : bv[i - 2048]);
    ball[i] = v;
  }
}

// ---------------- GEMM: C(M,NCOLS) = A(M,1024) @ Bt(NCOLS,1024)^T + bias ------
// m97 structure: 128x128 tile, BK=64, 4 waves, 16x16x32 bf16 MFMA,
// global_load_lds w=16 with pre-swizzled source, XOR slot swizzle on reads.
// MODE 0: f32 output (out-proj).
// MODE 2: QKV fused output (Q,K rows; V transposed into Vt) + mask all-ones
//         check INTERLEAVED into the k-loop (one int4 load per k-step, hidden
//         under the MFMA phase -> no serial scan tail; verified R9: -9 us).
template <int MODE>
__global__ __launch_bounds__(256) void gemm_bt(const bf16* __restrict__ A,
                                               const bf16* __restrict__ Bt,
                                               const float* __restrict__ bias,
                                               void* __restrict__ Cout, int ldc,
                                               bf16* __restrict__ Vt,
                                               const int4* __restrict__ mask4,
                                               int* __restrict__ flag) {
  constexpr int K = 1024;
  constexpr int BM = 128, BN = 128, BK = 64;
  __shared__ bf16 As[BM * BK];
  __shared__ bf16 Bs[BN * BK];
  const int tid = threadIdx.x;
  const int w = tid >> 6, l = tid & 63;
  const int wm = w >> 1, wn = w & 1;
  const int by = blockIdx.x, bx = blockIdx.y;   // swapped for XCD panel reuse

  f32x4 acc[4][4] = {};

  const int sRow = l >> 3;
  const int sSlot = (l & 7) ^ sRow;   // inverse-swizzled source slot
  const bf16* aBase = A + (size_t)(by * BM + w * 32 + sRow) * K + sSlot * 8;
  const bf16* bBase = Bt + (size_t)(bx * BN + w * 32 + sRow) * K + sSlot * 8;

  // mask-scan state (MODE 2): 11 strided int4 loads spread over 16 k-steps
  const int n4 = BB * SS * SS / 4;
  int mi = (by * 24 + bx) * 256 + tid;   // grid is (64,24) for MODE 2
  int ok = 1;
  int kiter = 0;

  for (int k0 = 0; k0 < K; k0 += BK) {
    int4 mv = {1, 1, 1, 1};
    bool have = (MODE == 2) && (kiter < 11) && (mi < n4);
    if (have) mv = mask4[mi];

    #pragma unroll
    for (int c = 0; c < 4; c++) {
      gload_lds16(aBase + (size_t)(c * 8) * K + k0, &As[(w * 32 + c * 8) * BK]);
      gload_lds16(bBase + (size_t)(c * 8) * K + k0, &Bs[(w * 32 + c * 8) * BK]);
    }
    __syncthreads();
    #pragma unroll
    for (int kk = 0; kk < 2; kk++) {
      bf16x8 af[4], bfr[4];
      #pragma unroll
      for (int i = 0; i < 4; i++) {
        int row = wm * 64 + i * 16 + (l & 15);
        int sl = (kk * 4 + (l >> 4)) ^ (row & 7);
        af[i] = *(const bf16x8*)(&As[row * BK + sl * 8]);
      }
      #pragma unroll
      for (int j = 0; j < 4; j++) {
        int row = wn * 64 + j * 16 + (l & 15);
        int sl = (kk * 4 + (l >> 4)) ^ (row & 7);
        bfr[j] = *(const bf16x8*)(&Bs[row * BK + sl * 8]);
      }
      #pragma unroll
      for (int i = 0; i < 4; i++)
        #pragma unroll
        for (int j = 0; j < 4; j++)
          acc[i][j] = __builtin_amdgcn_mfma_f32_16x16x32_bf16(af[i], bfr[j],
                                                              acc[i][j], 0, 0, 0);
    }
    __syncthreads();

    if (have) {
      if (!(mv.x && mv.y && mv.z && mv.w)) ok = 0;
      mi += 1536 * 256;
    }
    kiter++;
  }

  if (MODE == 2 && bx >= 16) {
    // V columns: transposed write into Vt (packed bf16x4 along s)
    #pragma unroll
    for (int j = 0; j < 4; j++) {
      int col = bx * BN + wn * 64 + j * 16 + (l & 15);
      int n = col - 2048;
      float bb = bias[col];
      #pragma unroll
      for (int i = 0; i < 4; i++) {
        int row0 = by * BM + wm * 64 + i * 16 + (l >> 4) * 4;
        int b_ = row0 >> 11;
        int s0 = row0 & 2047;
        bf16x4 vv;
        #pragma unroll
        for (int r = 0; r < 4; r++) vv[r] = (bf16)(acc[i][j][r] + bb);
        *(bf16x4*)&Vt[(size_t)(b_ * 1024 + n) * SS + s0] = vv;
      }
    }
  } else {
    #pragma unroll
    for (int j = 0; j < 4; j++) {
      int col = bx * BN + wn * 64 + j * 16 + (l & 15);
      float bb = bias[col];
      #pragma unroll
      for (int i = 0; i < 4; i++) {
        int row0 = by * BM + wm * 64 + i * 16 + (l >> 4) * 4;
        #pragma unroll
        for (int r = 0; r < 4; r++) {
          float v = acc[i][j][r] + bb;
          if (MODE == 2)
            ((bf16*)Cout)[(size_t)(row0 + r) * ldc + col] = (bf16)v;
          else
            ((float*)Cout)[(size_t)(row0 + r) * ldc + col] = v;
        }
      }
    }
  }

  if (MODE == 2) {
    if (__ballot(!ok)) {
      if ((tid & 63) == 0) atomicAnd(flag, 0);
    }
  }
}

// ---------------- fused flash attention ----------------
// R6 16x16 structure (proven 77 us, 0 conflicts) at DOUBLED occupancy:
// grid (B*H, S/128): 4 waves x 32 q-rows (2 q-blocks) = 128 q/block;
// 1024 blocks = 4 independent blocks/CU x 4 waves = 16 waves/CU (4/SIMD).
// R7/R9 post-mortems: attn time ~ sum of pipes (MFMA 37us + LDS + VALU) at
// 8 waves/CU -- lockstep phases never overlap. 4 waves/SIMD from independent
// blocks gives the TLP to overlap softmax(trans/VALU) with MFMA.
// K/V 64-wide tiles double-buffered (counted vmcnt(4) + raw barriers).
// Swapped-operand QK^T with PERMUTED K rows in LDS (t=32kk+8g+4c+r at LDS row
// m=32kk+16c+4g+r): lane (g,q)'s S^T outputs ARE its PV B-fragment
// (frag j = s4[2kk+(j>>2)][j&3] <-> t=32kk+8g+j) -> P never touches LDS.
// Max-free softmax in exp2 domain; denominator via ones-MFMA.
__global__ __launch_bounds__(256, 4) void attn_fwd(const bf16* __restrict__ QKV,
                                                   const bf16* __restrict__ Vt,
                                                   const int* __restrict__ mask,
                                                   const int* __restrict__ flag,
                                                   bf16* __restrict__ att) {
  __shared__ bf16 Ks[2][64 * 64];
  __shared__ bf16 Vs[2][64 * 64];
  const int tid = threadIdx.x, w = tid >> 6, l = tid & 63;
  const int g = l >> 4, q = l & 15;
  const int bh = blockIdx.x, b = bh >> 4, h = bh & 15;
  const int q0 = blockIdx.y * 128 + w * 32;   // this wave's 32 q-rows
  const bool allones = (*flag != 0);

  // Q B-fragments for two 16-col q-blocks (col=q, k = kk*32 + g*8 + j)
  bf16x8 bq[2][2];
  #pragma unroll
  for (int qb = 0; qb < 2; qb++) {
    const bf16* qptr =
        QKV + (size_t)(b * SS + q0 + qb * 16 + q) * LDQ + h * 64 + g * 8;
    bq[qb][0] = *(const bf16x8*)qptr;
    bq[qb][1] = *(const bf16x8*)(qptr + 32);
  }

  bf16x8 ones;
  #pragma unroll
  for (int j = 0; j < 8; j++) ones[j] = (bf16)1.0f;

  f32x4 o[2][4] = {};
  f32x4 ls[2] = {};   // softmax denominators (all 4 components identical)

  const int sSlot = (l & 7) ^ ((l >> 3) & 7);
  // permuted K-row source: gload block B8 = 2w+c covers LDS rows B8*8..+7;
  // lane fetches global tile-row t = 32*(B8>>2)+16*(B8&1)+4*((B8>>1)&1)
  //                                  + 8*(l>>5) + ((l>>3)&3)
  const bf16* kPtr[2];
  #pragma unroll
  for (int c = 0; c < 2; c++) {
    int B8 = 2 * w + c;
    int tl = 32 * (B8 >> 2) + 16 * (B8 & 1) + 4 * ((B8 >> 1) & 1) +
             8 * (l >> 5) + ((l >> 3) & 3);
    kPtr[c] = QKV + (size_t)(b * SS + tl) * LDQ + 1024 + h * 64 + sSlot * 8;
  }
  const bf16* vBase =
      Vt + (size_t)(b * 1024 + h * 64 + w * 16 + (l >> 3)) * SS + sSlot * 8;

  // prologue: stage tile 0 into buffer 0
  gload_lds16(kPtr[0], &Ks[0][(2 * w + 0) * 8 * 64]);
  gload_lds16(kPtr[1], &Ks[0][(2 * w + 1) * 8 * 64]);
  gload_lds16(vBase, &Vs[0][(w * 16) * 64]);
  gload_lds16(vBase + (size_t)8 * SS, &Vs[0][(w * 16 + 8) * 64]);

  for (int it = 0; it < NT; ++it) {
    const int cur = it & 1;
    if (it + 1 < NT) {   // stage next tile, wait only for cur's loads
      const int t1 = (it + 1) * 64;
      gload_lds16(kPtr[0] + (size_t)t1 * LDQ, &Ks[cur ^ 1][(2 * w + 0) * 8 * 64]);
      gload_lds16(kPtr[1] + (size_t)t1 * LDQ, &Ks[cur ^ 1][(2 * w + 1) * 8 * 64]);
      gload_lds16(vBase + t1, &Vs[cur ^ 1][(w * 16) * 64]);
      gload_lds16(vBase + (size_t)8 * SS + t1, &Vs[cur ^ 1][(w * 16 + 8) * 64]);
      asm volatile("s_waitcnt vmcnt(4)" ::: "memory");
    } else {
      asm volatile("s_waitcnt vmcnt(0)" ::: "memory");
    }
    __builtin_amdgcn_s_barrier();
    asm volatile("" ::: "memory");

    const bf16* ks = Ks[cur];
    const bf16* vs = Vs[cur];

    // register-cache the 8 K fragments once; reused by both q-blocks
    bf16x8 af[4][2];
    #pragma unroll
    for (int tt = 0; tt < 4; tt++) {
      int row = tt * 16 + q;
      af[tt][0] = *(const bf16x8*)(&ks[row * 64 + (g ^ (q & 7)) * 8]);
      af[tt][1] = *(const bf16x8*)(&ks[row * 64 + (((4 + g) ^ (q & 7))) * 8]);
    }

    // per q-block: S^T = K Q^T -> softmax -> PV B-fragments + ones-MFMA lsum.
    bf16x8 pb[2][2];
    #pragma unroll
    for (int qb = 0; qb < 2; qb++) {
      f32x4 s4[4];
      #pragma unroll
      for (int tt = 0; tt < 4; tt++) {
        f32x4 z = {};
        z = __builtin_amdgcn_mfma_f32_16x16x32_bf16(af[tt][0], bq[qb][0], z, 0, 0, 0);
        z = __builtin_amdgcn_mfma_f32_16x16x32_bf16(af[tt][1], bq[qb][1], z, 0, 0, 0);
        s4[tt] = z;
      }

      if (!allones) {  // masked fallback; m-row -> actual t: t=32kk+8g+4c+r
        const int t0 = it * 64;
        #pragma unroll
        for (int tt = 0; tt < 4; tt++)
          #pragma unroll
          for (int r = 0; r < 4; r++) {
            int tl = 32 * (tt >> 1) + 8 * g + 4 * (tt & 1) + r;
            if (mask[(size_t)(b * SS + q0 + qb * 16 + q) * SS + t0 + tl] == 0)
              s4[tt][r] = -1e30f;
          }
      }

      // max-free softmax; build PV B-fragments directly from s4
      #pragma unroll
      for (int kk = 0; kk < 2; kk++) {
        bf16x8 f;
        #pragma unroll
        for (int j = 0; j < 8; j++)
          f[j] = (bf16)fexp2(s4[2 * kk + (j >> 2)][j & 3]);
        pb[qb][kk] = f;
      }
      // denominator: ls[qb] += ones @ P  (column sums, replicated rows)
      ls[qb] = __builtin_amdgcn_mfma_f32_16x16x32_bf16(ones, pb[qb][0], ls[qb], 0, 0, 0);
      ls[qb] = __builtin_amdgcn_mfma_f32_16x16x32_bf16(ones, pb[qb][1], ls[qb], 0, 0, 0);
    }

    // ---- O^T += V^T P^T (each V read feeds both q-blocks) ----
    __builtin_amdgcn_s_setprio(1);
    #pragma unroll
    for (int kk = 0; kk < 2; kk++) {
      int cc = kk * 4 + g;
      #pragma unroll
      for (int n = 0; n < 4; n++) {
        int vrow = n * 16 + q;
        int vsl = cc ^ (q & 7);
        bf16x8 av = *(const bf16x8*)(&vs[vrow * 64 + vsl * 8]);
        o[0][n] = __builtin_amdgcn_mfma_f32_16x16x32_bf16(av, pb[0][kk], o[0][n], 0, 0, 0);
        o[1][n] = __builtin_amdgcn_mfma_f32_16x16x32_bf16(av, pb[1][kk], o[1][n], 0, 0, 0);
      }
    }
    __builtin_amdgcn_s_setprio(0);

    asm volatile("" ::: "memory");
    __builtin_amdgcn_s_barrier();
    asm volatile("" ::: "memory");
  }

  // normalize + store (ls already summed over ALL t and all lane-groups)
  #pragma unroll
  for (int qb = 0; qb < 2; qb++) {
    float inv = 1.0f / ls[qb][0];
    #pragma unroll
    for (int n = 0; n < 4; n++) {
      bf16x4 ov;
      #pragma unroll
      for (int r = 0; r < 4; r++) ov[r] = (bf16)(o[qb][n][r] * inv);
      *(bf16x4*)&att[(size_t)(b * SS + q0 + qb * 16 + q) * DD + h * 64 +
                     n * 16 + g * 4] = ov;
    }
  }
}

// ---------------- launch ----------------
extern "C" void kernel_launch(void* const* d_in, const int* in_sizes, int n_in,
                              void* d_out, int out_size, void* d_ws, size_t ws_size,
                              hipStream_t stream) {
  const float* x = (const float*)d_in[0];
  const int* mask = (const int*)d_in[1];
  const float* Wq = (const float*)d_in[2];
  const float* bq = (const float*)d_in[3];
  const float* Wk = (const float*)d_in[4];
  const float* bk = (const float*)d_in[5];
  const float* Wv = (const float*)d_in[6];
  const float* bv = (const float*)d_in[7];
  const float* Wo = (const float*)d_in[8];
  const float* bo = (const float*)d_in[9];
  float* out = (float*)d_out;

  char* p = (char*)d_ws;
  const size_t MB16 = (size_t)MM * DD * 2;        // 16 MiB
  bf16* xb = (bf16*)p;   p += MB16;               // reused as `att` later
  bf16* QKV = (bf16*)p;  p += (size_t)MM * LDQ * 2;  // 48 MiB (V third unused)
  bf16* Vt = (bf16*)p;   p += MB16;
  bf16* Wt_all = (bf16*)p; p += (size_t)3072 * DD * 2;  // Wq|Wk|Wv transposed
  bf16* Wot = (bf16*)p;  p += (size_t)DD * DD * 2;
  float* ball = (float*)p; p += 3072 * 4;
  int* flag = (int*)p;
  bf16* att = xb;  // xb dead after QKV projection

  // 1) fused prep: cvt_x (4096 blocks) | wtrans x4 (1024) | bias+flag (12)
  prep<<<5132, 256, 0, stream>>>(x, xb, Wq, Wk, Wv, Wo, Wt_all, Wot,
                                 bq, bk, bv, ball, flag);
  // 2) fused QKV projection + transposed-V write + in-loop mask scan
  gemm_bt<2><<<dim3(64, 24), 256, 0, stream>>>(xb, Wt_all, ball, QKV, LDQ,
                                               Vt, (const int4*)mask, flag);
  // 3) attention (16x16, 4 blocks/CU)
  attn_fwd<<<dim3(BB * HH, SS / 128), 256, 0, stream>>>(QKV, Vt, mask, flag, att);
  // 4) output projection
  gemm_bt<0><<<dim3(64, 8), 256, 0, stream>>>(att, Wot, bo, out, DD,
                                              Vt, (const int4*)mask, flag);
}

// Round 11
// 166.334 us; speedup vs baseline: 1.1324x; 1.1324x over previous
//
#include <hip/hip_runtime.h>
#include <hip/hip_bf16.h>

typedef __bf16 bf16;
typedef __bf16 bf16x4 __attribute__((ext_vector_type(4)));
typedef __bf16 bf16x8 __attribute__((ext_vector_type(8)));
typedef float f32x4 __attribute__((ext_vector_type(4)));

#define AS1 __attribute__((address_space(1)))
#define AS3 __attribute__((address_space(3)))

__device__ __forceinline__ void gload_lds16(const void* g, void* l) {
  __builtin_amdgcn_global_load_lds((const AS1 void*)g, (AS3 void*)l, 16, 0, 0);
}

__device__ __forceinline__ float fexp2(float x) {
#if __has_builtin(__builtin_amdgcn_exp2f)
  return __builtin_amdgcn_exp2f(x);
#else
  return exp2f(x);
#endif
}

// ---------------- problem constants ----------------
#define BB 4
#define SS 2048
#define DD 1024
#define HH 16
#define MM (BB*SS)          // 8192 rows
#define LDQ 3072            // QKV fused row stride
#define NT (SS/64)          // K/V tiles per attention pass
// log2(e) / sqrt(64)  -- folded into Wq,bq so softmax runs in exp2 domain
#define QSCALE 0.18033688011112042f

// ---------------- fused prep kernel ----------------
// wtrans blocks FIRST (heavier; avoid forming the kernel's tail), then cvt_x,
// then bias concat + flag init.
__global__ __launch_bounds__(256) void prep(
    const float* __restrict__ x, bf16* __restrict__ xb,
    const float* __restrict__ Wq, const float* __restrict__ Wk,
    const float* __restrict__ Wv, const float* __restrict__ Wo,
    bf16* __restrict__ WtQKV, bf16* __restrict__ Wto,
    const float* __restrict__ bq, const float* __restrict__ bk,
    const float* __restrict__ bv, float* __restrict__ ball,
    int* __restrict__ flag) {
  __shared__ float t[64][65];
  const int bid = blockIdx.x;
  if (bid < 1024) {            // ---- wtrans ----
    int id = bid;
    int which = id >> 8;
    int bi = (id >> 4) & 15, bj = id & 15;   // bi: k-tile, bj: n-tile
    const float* W = which == 0 ? Wq : which == 1 ? Wk : which == 2 ? Wv : Wo;
    bf16* Wt = which < 3 ? WtQKV + (size_t)which * 1024 * DD : Wto;
    const float scale = (which == 0) ? QSCALE : 1.0f;
    for (int c = 0; c < 16; c++) {
      int idx = threadIdx.x + c * 256;
      int r = idx >> 6, col = idx & 63;
      t[r][col] = W[(size_t)(bi * 64 + r) * DD + bj * 64 + col];
    }
    __syncthreads();
    for (int c = 0; c < 16; c++) {
      int idx = threadIdx.x + c * 256;
      int rn = idx >> 6, ck = idx & 63;
      Wt[(size_t)(bj * 64 + rn) * DD + bi * 64 + ck] = (bf16)(t[ck][rn] * scale);
    }
  } else if (bid < 5120) {     // ---- cvt_x ----
    int i = ((bid - 1024) * 256 + threadIdx.x) * 8;
    float4 a = *(const float4*)&x[i];
    float4 b = *(const float4*)&x[i + 4];
    bf16x8 o;
    o[0] = (bf16)a.x; o[1] = (bf16)a.y; o[2] = (bf16)a.z; o[3] = (bf16)a.w;
    o[4] = (bf16)b.x; o[5] = (bf16)b.y; o[6] = (bf16)b.z; o[7] = (bf16)b.w;
    *(bf16x8*)&xb[i] = o;
  } else {                     // ---- bias concat + flag init ----
    int i = (bid - 5120) * 256 + threadIdx.x;
    if (i == 0) *flag = 1;
    float v = (i < 1024) ? bq[i] * QSCALE
                         : ((i < 2048) ? bk[i - 1024] : bv[i - 2048]);
    ball[i] = v;
  }
}

// ---------------- GEMM: C(M,NCOLS) = A(M,1024) @ Bt(NCOLS,1024)^T + bias ------
// m97 structure: 128x128 tile, BK=64, 4 waves, 16x16x32 bf16 MFMA,
// global_load_lds w=16 with pre-swizzled source, XOR slot swizzle on reads.
// MODE 0: f32 output (out-proj).
// MODE 2: QKV fused output (Q,K rows; V transposed into Vt) + mask all-ones
//         check INTERLEAVED into the k-loop (one int4 load per k-step, hidden
//         under the MFMA phase -> no serial scan tail; verified R9).
template <int MODE>
__global__ __launch_bounds__(256) void gemm_bt(const bf16* __restrict__ A,
                                               const bf16* __restrict__ Bt,
                                               const float* __restrict__ bias,
                                               void* __restrict__ Cout, int ldc,
                                               bf16* __restrict__ Vt,
                                               const int4* __restrict__ mask4,
                                               int* __restrict__ flag) {
  constexpr int K = 1024;
  constexpr int BM = 128, BN = 128, BK = 64;
  __shared__ bf16 As[BM * BK];
  __shared__ bf16 Bs[BN * BK];
  const int tid = threadIdx.x;
  const int w = tid >> 6, l = tid & 63;
  const int wm = w >> 1, wn = w & 1;
  const int by = blockIdx.x, bx = blockIdx.y;   // swapped for XCD panel reuse

  f32x4 acc[4][4] = {};

  const int sRow = l >> 3;
  const int sSlot = (l & 7) ^ sRow;   // inverse-swizzled source slot
  const bf16* aBase = A + (size_t)(by * BM + w * 32 + sRow) * K + sSlot * 8;
  const bf16* bBase = Bt + (size_t)(bx * BN + w * 32 + sRow) * K + sSlot * 8;

  // mask-scan state (MODE 2): 11 strided int4 loads spread over 16 k-steps
  const int n4 = BB * SS * SS / 4;
  int mi = (by * 24 + bx) * 256 + tid;   // grid is (64,24) for MODE 2
  int ok = 1;
  int kiter = 0;

  for (int k0 = 0; k0 < K; k0 += BK) {
    int4 mv = {1, 1, 1, 1};
    bool have = (MODE == 2) && (kiter < 11) && (mi < n4);
    if (have) mv = mask4[mi];

    #pragma unroll
    for (int c = 0; c < 4; c++) {
      gload_lds16(aBase + (size_t)(c * 8) * K + k0, &As[(w * 32 + c * 8) * BK]);
      gload_lds16(bBase + (size_t)(c * 8) * K + k0, &Bs[(w * 32 + c * 8) * BK]);
    }
    __syncthreads();
    #pragma unroll
    for (int kk = 0; kk < 2; kk++) {
      bf16x8 af[4], bfr[4];
      #pragma unroll
      for (int i = 0; i < 4; i++) {
        int row = wm * 64 + i * 16 + (l & 15);
        int sl = (kk * 4 + (l >> 4)) ^ (row & 7);
        af[i] = *(const bf16x8*)(&As[row * BK + sl * 8]);
      }
      #pragma unroll
      for (int j = 0; j < 4; j++) {
        int row = wn * 64 + j * 16 + (l & 15);
        int sl = (kk * 4 + (l >> 4)) ^ (row & 7);
        bfr[j] = *(const bf16x8*)(&Bs[row * BK + sl * 8]);
      }
      #pragma unroll
      for (int i = 0; i < 4; i++)
        #pragma unroll
        for (int j = 0; j < 4; j++)
          acc[i][j] = __builtin_amdgcn_mfma_f32_16x16x32_bf16(af[i], bfr[j],
                                                              acc[i][j], 0, 0, 0);
    }
    __syncthreads();

    if (have) {
      if (!(mv.x && mv.y && mv.z && mv.w)) ok = 0;
      mi += 1536 * 256;
    }
    kiter++;
  }

  if (MODE == 2 && bx >= 16) {
    // V columns: transposed write into Vt (packed bf16x4 along s)
    #pragma unroll
    for (int j = 0; j < 4; j++) {
      int col = bx * BN + wn * 64 + j * 16 + (l & 15);
      int n = col - 2048;
      float bb = bias[col];
      #pragma unroll
      for (int i = 0; i < 4; i++) {
        int row0 = by * BM + wm * 64 + i * 16 + (l >> 4) * 4;
        int b_ = row0 >> 11;
        int s0 = row0 & 2047;
        bf16x4 vv;
        #pragma unroll
        for (int r = 0; r < 4; r++) vv[r] = (bf16)(acc[i][j][r] + bb);
        *(bf16x4*)&Vt[(size_t)(b_ * 1024 + n) * SS + s0] = vv;
      }
    }
  } else {
    #pragma unroll
    for (int j = 0; j < 4; j++) {
      int col = bx * BN + wn * 64 + j * 16 + (l & 15);
      float bb = bias[col];
      #pragma unroll
      for (int i = 0; i < 4; i++) {
        int row0 = by * BM + wm * 64 + i * 16 + (l >> 4) * 4;
        #pragma unroll
        for (int r = 0; r < 4; r++) {
          float v = acc[i][j][r] + bb;
          if (MODE == 2)
            ((bf16*)Cout)[(size_t)(row0 + r) * ldc + col] = (bf16)v;
          else
            ((float*)Cout)[(size_t)(row0 + r) * ldc + col] = v;
        }
      }
    }
  }

  if (MODE == 2) {
    if (__ballot(!ok)) {
      if ((tid & 63) == 0) atomicAnd(flag, 0);
    }
  }
}

// ---------------- fused flash attention (R6 structure, proven 77 us) ---------
// grid (B*H, S/256): 4 waves x 64 q-rows (4 q-blocks) = 256 q/block; 2 blk/CU.
// R7(2-wave)/R10(4-blk) occupancy experiments both regressed: this config is
// the measured optimum (LDS amortization x L2 footprint x TLP).
// K/V 64-wide tiles double-buffered (counted vmcnt(4) + raw barriers).
// Swapped-operand QK^T with PERMUTED K rows in LDS (t=32kk+8g+4c+r at LDS row
// m=32kk+16c+4g+r): lane (g,q)'s S^T outputs ARE its PV B-fragment
// (frag j = s4[2kk+(j>>2)][j&3] <-> t=32kk+8g+j) -> P never touches LDS.
// K fragments register-cached once per tile, reused by all 4 q-blocks.
// Max-free softmax in exp2 domain (scores pre-scaled via Wq); denominator via
// ones-MFMA (column sums replicated -> no add chains, no end shuffles).
__global__ __launch_bounds__(256, 2) void attn_fwd(const bf16* __restrict__ QKV,
                                                   const bf16* __restrict__ Vt,
                                                   const int* __restrict__ mask,
                                                   const int* __restrict__ flag,
                                                   bf16* __restrict__ att) {
  __shared__ bf16 Ks[2][64 * 64];
  __shared__ bf16 Vs[2][64 * 64];
  const int tid = threadIdx.x, w = tid >> 6, l = tid & 63;
  const int g = l >> 4, q = l & 15;
  const int bh = blockIdx.x, b = bh >> 4, h = bh & 15;
  const int q0 = blockIdx.y * 256 + w * 64;   // this wave's 64 q-rows
  const bool allones = (*flag != 0);

  // Q B-fragments for four 16-col q-blocks (col=q, k = kk*32 + g*8 + j)
  bf16x8 bq[4][2];
  #pragma unroll
  for (int qb = 0; qb < 4; qb++) {
    const bf16* qptr =
        QKV + (size_t)(b * SS + q0 + qb * 16 + q) * LDQ + h * 64 + g * 8;
    bq[qb][0] = *(const bf16x8*)qptr;
    bq[qb][1] = *(const bf16x8*)(qptr + 32);
  }

  bf16x8 ones;
  #pragma unroll
  for (int j = 0; j < 8; j++) ones[j] = (bf16)1.0f;

  f32x4 o[4][4] = {};
  f32x4 ls[4] = {};   // softmax denominators (all 4 components identical)

  const int sSlot = (l & 7) ^ ((l >> 3) & 7);
  // permuted K-row source: gload block B8 = 2w+c covers LDS rows B8*8..+7;
  // lane fetches global tile-row t = 32*(B8>>2)+16*(B8&1)+4*((B8>>1)&1)
  //                                  + 8*(l>>5) + ((l>>3)&3)
  const bf16* kPtr[2];
  #pragma unroll
  for (int c = 0; c < 2; c++) {
    int B8 = 2 * w + c;
    int tl = 32 * (B8 >> 2) + 16 * (B8 & 1) + 4 * ((B8 >> 1) & 1) +
             8 * (l >> 5) + ((l >> 3) & 3);
    kPtr[c] = QKV + (size_t)(b * SS + tl) * LDQ + 1024 + h * 64 + sSlot * 8;
  }
  const bf16* vBase =
      Vt + (size_t)(b * 1024 + h * 64 + w * 16 + (l >> 3)) * SS + sSlot * 8;

  // prologue: stage tile 0 into buffer 0
  gload_lds16(kPtr[0], &Ks[0][(2 * w + 0) * 8 * 64]);
  gload_lds16(kPtr[1], &Ks[0][(2 * w + 1) * 8 * 64]);
  gload_lds16(vBase, &Vs[0][(w * 16) * 64]);
  gload_lds16(vBase + (size_t)8 * SS, &Vs[0][(w * 16 + 8) * 64]);

  for (int it = 0; it < NT; ++it) {
    const int cur = it & 1;
    if (it + 1 < NT) {   // stage next tile, wait only for cur's loads
      const int t1 = (it + 1) * 64;
      gload_lds16(kPtr[0] + (size_t)t1 * LDQ, &Ks[cur ^ 1][(2 * w + 0) * 8 * 64]);
      gload_lds16(kPtr[1] + (size_t)t1 * LDQ, &Ks[cur ^ 1][(2 * w + 1) * 8 * 64]);
      gload_lds16(vBase + t1, &Vs[cur ^ 1][(w * 16) * 64]);
      gload_lds16(vBase + (size_t)8 * SS + t1, &Vs[cur ^ 1][(w * 16 + 8) * 64]);
      asm volatile("s_waitcnt vmcnt(4)" ::: "memory");
    } else {
      asm volatile("s_waitcnt vmcnt(0)" ::: "memory");
    }
    __builtin_amdgcn_s_barrier();
    asm volatile("" ::: "memory");

    const bf16* ks = Ks[cur];
    const bf16* vs = Vs[cur];

    // register-cache the 8 K fragments once; reused by all 4 q-blocks
    bf16x8 af[4][2];
    #pragma unroll
    for (int tt = 0; tt < 4; tt++) {
      int row = tt * 16 + q;
      af[tt][0] = *(const bf16x8*)(&ks[row * 64 + (g ^ (q & 7)) * 8]);
      af[tt][1] = *(const bf16x8*)(&ks[row * 64 + (((4 + g) ^ (q & 7))) * 8]);
    }

    // per q-block: S^T = K Q^T -> softmax -> PV B-fragments + ones-MFMA lsum.
    // Straight-line region, no fences: qb-independent work overlaps pipes.
    bf16x8 pb[4][2];
    #pragma unroll
    for (int qb = 0; qb < 4; qb++) {
      f32x4 s4[4];
      #pragma unroll
      for (int tt = 0; tt < 4; tt++) {
        f32x4 z = {};
        z = __builtin_amdgcn_mfma_f32_16x16x32_bf16(af[tt][0], bq[qb][0], z, 0, 0, 0);
        z = __builtin_amdgcn_mfma_f32_16x16x32_bf16(af[tt][1], bq[qb][1], z, 0, 0, 0);
        s4[tt] = z;
      }

      if (!allones) {  // masked fallback; m-row -> actual t: t=32kk+8g+4c+r
        const int t0 = it * 64;
        #pragma unroll
        for (int tt = 0; tt < 4; tt++)
          #pragma unroll
          for (int r = 0; r < 4; r++) {
            int tl = 32 * (tt >> 1) + 8 * g + 4 * (tt & 1) + r;
            if (mask[(size_t)(b * SS + q0 + qb * 16 + q) * SS + t0 + tl] == 0)
              s4[tt][r] = -1e30f;
          }
      }

      // max-free softmax; build PV B-fragments directly from s4
      #pragma unroll
      for (int kk = 0; kk < 2; kk++) {
        bf16x8 f;
        #pragma unroll
        for (int j = 0; j < 8; j++)
          f[j] = (bf16)fexp2(s4[2 * kk + (j >> 2)][j & 3]);
        pb[qb][kk] = f;
      }
      // denominator: ls[qb] += ones @ P  (column sums, replicated rows)
      ls[qb] = __builtin_amdgcn_mfma_f32_16x16x32_bf16(ones, pb[qb][0], ls[qb], 0, 0, 0);
      ls[qb] = __builtin_amdgcn_mfma_f32_16x16x32_bf16(ones, pb[qb][1], ls[qb], 0, 0, 0);
    }

    // ---- O^T += V^T P^T (each V read feeds 4 q-blocks) ----
    __builtin_amdgcn_s_setprio(1);
    #pragma unroll
    for (int kk = 0; kk < 2; kk++) {
      int cc = kk * 4 + g;
      #pragma unroll
      for (int n = 0; n < 4; n++) {
        int vrow = n * 16 + q;
        int vsl = cc ^ (q & 7);
        bf16x8 av = *(const bf16x8*)(&vs[vrow * 64 + vsl * 8]);
        #pragma unroll
        for (int qb = 0; qb < 4; qb++)
          o[qb][n] = __builtin_amdgcn_mfma_f32_16x16x32_bf16(av, pb[qb][kk],
                                                             o[qb][n], 0, 0, 0);
      }
    }
    __builtin_amdgcn_s_setprio(0);

    asm volatile("" ::: "memory");
    __builtin_amdgcn_s_barrier();
    asm volatile("" ::: "memory");
  }

  // normalize + store (ls already summed over ALL t and all lane-groups)
  #pragma unroll
  for (int qb = 0; qb < 4; qb++) {
    float inv = 1.0f / ls[qb][0];
    #pragma unroll
    for (int n = 0; n < 4; n++) {
      bf16x4 ov;
      #pragma unroll
      for (int r = 0; r < 4; r++) ov[r] = (bf16)(o[qb][n][r] * inv);
      *(bf16x4*)&att[(size_t)(b * SS + q0 + qb * 16 + q) * DD + h * 64 +
                     n * 16 + g * 4] = ov;
    }
  }
}

// ---------------- launch ----------------
extern "C" void kernel_launch(void* const* d_in, const int* in_sizes, int n_in,
                              void* d_out, int out_size, void* d_ws, size_t ws_size,
                              hipStream_t stream) {
  const float* x = (const float*)d_in[0];
  const int* mask = (const int*)d_in[1];
  const float* Wq = (const float*)d_in[2];
  const float* bq = (const float*)d_in[3];
  const float* Wk = (const float*)d_in[4];
  const float* bk = (const float*)d_in[5];
  const float* Wv = (const float*)d_in[6];
  const float* bv = (const float*)d_in[7];
  const float* Wo = (const float*)d_in[8];
  const float* bo = (const float*)d_in[9];
  float* out = (float*)d_out;

  char* p = (char*)d_ws;
  const size_t MB16 = (size_t)MM * DD * 2;        // 16 MiB
  bf16* xb = (bf16*)p;   p += MB16;               // reused as `att` later
  bf16* QKV = (bf16*)p;  p += (size_t)MM * LDQ * 2;  // 48 MiB (V third unused)
  bf16* Vt = (bf16*)p;   p += MB16;
  bf16* Wt_all = (bf16*)p; p += (size_t)3072 * DD * 2;  // Wq|Wk|Wv transposed
  bf16* Wot = (bf16*)p;  p += (size_t)DD * DD * 2;
  float* ball = (float*)p; p += 3072 * 4;
  int* flag = (int*)p;
  bf16* att = xb;  // xb dead after QKV projection

  // 1) fused prep: wtrans x4 (1024 blocks) | cvt_x (4096) | bias+flag (12)
  prep<<<5132, 256, 0, stream>>>(x, xb, Wq, Wk, Wv, Wo, Wt_all, Wot,
                                 bq, bk, bv, ball, flag);
  // 2) fused QKV projection + transposed-V write + in-loop mask scan
  gemm_bt<2><<<dim3(64, 24), 256, 0, stream>>>(xb, Wt_all, ball, QKV, LDQ,
                                               Vt, (const int4*)mask, flag);
  // 3) attention (16x16, proven R6 config)
  attn_fwd<<<dim3(BB * HH, SS / 256), 256, 0, stream>>>(QKV, Vt, mask, flag, att);
  // 4) output projection
  gemm_bt<0><<<dim3(64, 8), 256, 0, stream>>>(att, Wot, bo, out, DD,
                                              Vt, (const int4*)mask, flag);
}